// Round 20
// baseline (39.041 us; speedup 1.0000x reference)
//
#include <hip/hip_runtime.h>
#include <hip/hip_bf16.h>
#include <math.h>

#define BB 4
#define HH 128
#define WW 128
#define CIN 64
#define COUT 64
#define KK 9
#define OMC 27
#define NPIX (BB * HH * WW)

typedef __attribute__((ext_vector_type(8))) short bf16x8;
typedef __attribute__((ext_vector_type(4))) float f32x4;

static __device__ __forceinline__ unsigned int pkcvt(float a, float b) {
    __hip_bfloat162 h = __float22bfloat162_rn(make_float2(a, b));
    return *reinterpret_cast<unsigned int*>(&h);
}
static __device__ __forceinline__ float bflo(unsigned int u) {
    return __uint_as_float(u << 16);
}
static __device__ __forceinline__ float bfhi(unsigned int u) {
    return __uint_as_float(u & 0xffff0000u);
}

// ---------------------------------------------------------------------------
// Kernel 0: one-shot weight transforms (unchanged).
// ---------------------------------------------------------------------------
__global__ __launch_bounds__(64) void weight_transform(
    const float* __restrict__ wmain, const float* __restrict__ wofs,
    uint4* __restrict__ wb, uint4* __restrict__ wf)
{
    const int tg = blockIdx.x * 64 + threadIdx.x;
    if (tg < 4608) {
        const int lane = tg & 63;
        const int nf   = (tg >> 6) & 3;
        const int ks   = tg >> 8;
        const int k0   = ks * 32 + ((lane >> 4) * 8);
        const int n    = nf * 16 + (lane & 15);
        uint4 q;
        q.x = pkcvt(wmain[(size_t)(k0 + 0) * COUT + n], wmain[(size_t)(k0 + 1) * COUT + n]);
        q.y = pkcvt(wmain[(size_t)(k0 + 2) * COUT + n], wmain[(size_t)(k0 + 3) * COUT + n]);
        q.z = pkcvt(wmain[(size_t)(k0 + 4) * COUT + n], wmain[(size_t)(k0 + 5) * COUT + n]);
        q.w = pkcvt(wmain[(size_t)(k0 + 6) * COUT + n], wmain[(size_t)(k0 + 7) * COUT + n]);
        wb[tg] = q;
    } else {
        const int idx  = tg - 4608;
        const int lane = idx & 63;
        const int frag = idx >> 6;
        const int nf   = frag & 1;
        const int ks   = frag >> 1;
        const int t    = ks >> 1;
        const int kw   = ks & 1;
        const int j    = nf * 16 + (lane & 15);
        const int c0   = kw * 32 + ((lane >> 4) * 8);
        uint4 q;
        if (j < OMC) {
            const float* wp = wofs + ((size_t)t * CIN + c0) * OMC + j;
            q.x = pkcvt(wp[0 * OMC], wp[1 * OMC]);
            q.y = pkcvt(wp[2 * OMC], wp[3 * OMC]);
            q.z = pkcvt(wp[4 * OMC], wp[5 * OMC]);
            q.w = pkcvt(wp[6 * OMC], wp[7 * OMC]);
        } else {
            q.x = q.y = q.z = q.w = 0u;
        }
        wf[frag * 64 + lane] = q;
    }
}

// ---------------------------------------------------------------------------
// FUSED kernel (R19 structure) + phase-3 2-SLOT TAP PIPELINE:
// TLOAD(t+1) prefetches {entry, 4x ds_read_b128 corners, 4x wb B-frags}
// into named slot regs while TCONS(t) does unpack/bilinear-FMA/pack/MFMA.
// Covers the ~120cy LDS latency and ~200cy wb L2 latency that were serial
// inside every tap (R19's residual ~70% stall).  Rare out-of-tile entries
// (fl=1) take the exact global-clamped path inside TCONS.
// LDS 36864 B: xs5 23040 | om_s 3456 | ent 10368 (om_red/red overlays).
// 4 blocks/CU by LDS -> scheduler budget 128 VGPR; pipeline needs ~115.
// ---------------------------------------------------------------------------
#define TMB 32   // pixels per block

__global__ __launch_bounds__(256) void dcn_fused(
    const float* __restrict__ x,
    const uint4* __restrict__ wb,
    const uint4* __restrict__ wf,
    const float* __restrict__ bias,
    const float* __restrict__ bofs,
    float* __restrict__ out)
{
    __shared__ char shm[23040 + 3456 + 4608 + 4608 + 1152];  // 36864
    char*   xs5   = shm;                              // [0,23040)   ph0-3
    float*  om_s  = (float*)(shm + 23040);            // [23040,26496) ph1-2
    float4* ent_w = (float4*)(shm + 26496);           // ph2-3
    int4*   ent_o = (int4*)(shm + 31104);             // ph2-3
    int*    ent_f = (int*)(shm + 35712);              // ph2-3
    f32x4*  om_red = (f32x4*)(shm + 26496);           // ph1 reduce (pre-ent)
    f32x4*  red    = (f32x4*)shm;                     // ph4 (overlay xs5)

    const int tid  = threadIdx.x;
    const int lane = tid & 63;
    const int wv   = tid >> 6;
    const int pair = wv >> 1;
    const int kw   = wv & 1;
    const int bid  = ((blockIdx.x & 7) << 8) + (blockIdx.x >> 3);  // XCD chunk
    const int pix0 = bid * TMB;
    const int b    = pix0 >> 14;
    const int h    = (pix0 >> 7) & (HH - 1);
    const int w0   = pix0 & (WW - 1);
    const float* xb = x + (size_t)b * HH * WW * CIN;

    // ---- phase 0: stage x tile [5 rows][36 cols][64 ch] bf16, swizzled ----
    #pragma unroll
    for (int it = 0; it < 6; ++it) {
        const int idx = it * 256 + tid;
        if (idx < 1440) {
            const int c8   = idx & 7;
            const int cell = idx >> 3;          // [0,180)
            const int ty   = cell / 36;
            const int wi   = cell - ty * 36;
            const int hy   = h - 2 + ty;
            const int wcol = w0 - 2 + wi;
            uint4 q;
            if ((unsigned)hy < (unsigned)HH && (unsigned)wcol < (unsigned)WW) {
                const float* p = xb + ((size_t)hy * WW + wcol) * CIN + c8 * 8;
                const float4 a0 = *(const float4*)p;
                const float4 a1 = *(const float4*)(p + 4);
                q.x = pkcvt(a0.x, a0.y);
                q.y = pkcvt(a0.z, a0.w);
                q.z = pkcvt(a1.x, a1.y);
                q.w = pkcvt(a1.z, a1.w);
            } else {
                q.x = q.y = q.z = q.w = 0u;
            }
            const int off = cell * 128 + ((c8 * 16) ^ ((cell & 7) << 4));
            *(uint4*)(xs5 + off) = q;
        }
    }
    __syncthreads();

    // ---- phase 1: om GEMM (A from xs5 rows 1..3) ----
    f32x4 accm[2] = {};
    #pragma unroll
    for (int t = 0; t < KK; ++t) {
        const int ty = t / 3, tx = t % 3;
        const int cell = (ty + 1) * 36 + (pair * 16 + (lane & 15) + tx + 1);
        const int aoff = cell * 128 + ((kw * 64 + (lane >> 4) * 16) ^ ((cell & 7) << 4));
        const bf16x8 a = *(const bf16x8*)(xs5 + aoff);
        const uint4* wf0 = wf + ((t * 2 + kw) * 2) * 64 + lane;
        const bf16x8 b0 = *(const bf16x8*)(wf0);
        const bf16x8 b1 = *(const bf16x8*)(wf0 + 64);
        accm[0] = __builtin_amdgcn_mfma_f32_16x16x32_bf16(a, b0, accm[0], 0, 0, 0);
        accm[1] = __builtin_amdgcn_mfma_f32_16x16x32_bf16(a, b1, accm[1], 0, 0, 0);
    }

    if (kw == 1) {
        om_red[(pair * 2 + 0) * 64 + lane] = accm[0];
        om_red[(pair * 2 + 1) * 64 + lane] = accm[1];
    }
    __syncthreads();
    if (kw == 0) {
        #pragma unroll
        for (int nf = 0; nf < 2; ++nf) {
            const int j = nf * 16 + (lane & 15);
            if (j >= OMC) continue;
            const f32x4 o = om_red[(pair * 2 + nf) * 64 + lane];
            const float bb = bofs[j];
            const int m0 = pair * 16 + ((lane >> 4) * 4);
            #pragma unroll
            for (int r = 0; r < 4; ++r) {
                float val = accm[nf][r] + o[r] + bb;
                const int wpix = w0 + m0 + r;
                if (j < 18) {
                    const int t = j >> 1;
                    if ((j & 1) == 0) val += (float)(h - 1 + t / 3);     // abs py
                    else              val += (float)(wpix - 1 + t % 3);  // abs px
                } else {
                    val = 1.0f / (1.0f + __expf(-val));                  // sigmoid
                }
                om_s[(m0 + r) * OMC + j] = val;
            }
        }
    }
    __syncthreads();

    // ---- phase 2: entry precompute (LDS offsets when in-tile, else global) ----
    for (int e = tid; e < 288; e += 256) {
        const int px = e / 9;
        const int t  = e - px * 9;
        const float py  = om_s[px * OMC + 2 * t];
        const float pxx = om_s[px * OMC + 2 * t + 1];
        const float mk  = om_s[px * OMC + 18 + t];

        const float fy = floorf(py), fx = floorf(pxx);
        const int y0 = (int)fy, x0 = (int)fx;
        const float wy1 = py - fy, wx1 = pxx - fx;
        const float wy0 = 1.0f - wy1, wx0 = 1.0f - wx1;
        const bool vy0 = (unsigned)y0 < (unsigned)HH;
        const bool vy1 = (unsigned)(y0 + 1) < (unsigned)HH;
        const bool vx0 = (unsigned)x0 < (unsigned)WW;
        const bool vx1 = (unsigned)(x0 + 1) < (unsigned)WW;
        float4 w4;
        w4.x = (vy0 && vx0) ? wy0 * wx0 * mk : 0.0f;
        w4.y = (vy0 && vx1) ? wy0 * wx1 * mk : 0.0f;
        w4.z = (vy1 && vx0) ? wy1 * wx0 * mk : 0.0f;
        w4.w = (vy1 && vx1) ? wy1 * wx1 * mk : 0.0f;

        const int r0  = y0 - (h - 2);
        const int c0i = x0 - (w0 - 2);
        int4 o4;
        int fl;
        if ((unsigned)r0 <= 3u && (unsigned)c0i <= 34u) {
            const int base = r0 * 36 + c0i;
            o4.x = base * 128;
            o4.y = (base + 1) * 128;
            o4.z = (base + 36) * 128;
            o4.w = (base + 37) * 128;
            fl = 0;
        } else {
            const int yc0 = min(max(y0, 0), HH - 1);
            const int yc1 = min(max(y0 + 1, 0), HH - 1);
            const int xc0 = min(max(x0, 0), WW - 1);
            const int xc1 = min(max(x0 + 1, 0), WW - 1);
            o4.x = (yc0 * WW + xc0) * (CIN * 4);
            o4.y = (yc0 * WW + xc1) * (CIN * 4);
            o4.z = (yc1 * WW + xc0) * (CIN * 4);
            o4.w = (yc1 * WW + xc1) * (CIN * 4);
            fl = 1;
        }
        ent_w[e] = w4;
        ent_o[e] = o4;
        ent_f[e] = fl;
    }
    __syncthreads();

    // ---- phase 3: 2-slot tap pipeline: TLOAD(t+1) || TCONS(t) ----
    const int p   = lane & 15;            // A-frag pixel row
    const int g   = lane >> 4;            // channel group (8 ch)
    const int kwg = kw * 64 + g * 16;     // byte offset of this lane's 16B
    const char* xg = (const char*)xb + (size_t)(kw * 32 + g * 8) * 4;
    const int ebase = pair * 144 + p * 9;

    f32x4 acc[4] = {};

#define TLOAD(S, t) {                                                          \
        w4##S = ent_w[ebase + (t)];                                            \
        o4##S = ent_o[ebase + (t)];                                            \
        fl##S = ent_f[ebase + (t)];                                            \
        if (fl##S == 0) {                                                      \
            q0##S = *(const uint4*)(xs5 + o4##S.x + (kwg ^ ((o4##S.x >> 3) & 0x70))); \
            q1##S = *(const uint4*)(xs5 + o4##S.y + (kwg ^ ((o4##S.y >> 3) & 0x70))); \
            q2##S = *(const uint4*)(xs5 + o4##S.z + (kwg ^ ((o4##S.z >> 3) & 0x70))); \
            q3##S = *(const uint4*)(xs5 + o4##S.w + (kwg ^ ((o4##S.w >> 3) & 0x70))); \
        }                                                                      \
        const uint4* wbp = wb + (((t) * 2 + kw) * 4) * 64 + lane;              \
        b0##S = *(wbp + 0 * 64);                                               \
        b1##S = *(wbp + 1 * 64);                                               \
        b2##S = *(wbp + 2 * 64);                                               \
        b3##S = *(wbp + 3 * 64);                                               \
    }

#define TCONS(S) {                                                             \
        float s[8];                                                            \
        if (fl##S == 0) {                                                      \
            const unsigned int* u0 = (const unsigned int*)&q0##S;              \
            const unsigned int* u1 = (const unsigned int*)&q1##S;              \
            const unsigned int* u2 = (const unsigned int*)&q2##S;              \
            const unsigned int* u3 = (const unsigned int*)&q3##S;              \
            const float4 w4 = w4##S;                                           \
            _Pragma("unroll")                                                  \
            for (int i = 0; i < 4; ++i) {                                      \
                s[2 * i]     = w4.x * bflo(u0[i]) + w4.y * bflo(u1[i])         \
                             + w4.z * bflo(u2[i]) + w4.w * bflo(u3[i]);        \
                s[2 * i + 1] = w4.x * bfhi(u0[i]) + w4.y * bfhi(u1[i])         \
                             + w4.z * bfhi(u2[i]) + w4.w * bfhi(u3[i]);        \
            }                                                                  \
        } else {                                                               \
            const float4 w4 = w4##S;                                           \
            const float4 c0a = *(const float4*)(xg + o4##S.x);                 \
            const float4 c0b = *(const float4*)(xg + o4##S.x + 16);            \
            const float4 c1a = *(const float4*)(xg + o4##S.y);                 \
            const float4 c1b = *(const float4*)(xg + o4##S.y + 16);            \
            const float4 c2a = *(const float4*)(xg + o4##S.z);                 \
            const float4 c2b = *(const float4*)(xg + o4##S.z + 16);            \
            const float4 c3a = *(const float4*)(xg + o4##S.w);                 \
            const float4 c3b = *(const float4*)(xg + o4##S.w + 16);            \
            _Pragma("unroll")                                                  \
            for (int i = 0; i < 4; ++i) {                                      \
                s[i]     = w4.x * ((const float*)&c0a)[i] + w4.y * ((const float*)&c1a)[i] \
                         + w4.z * ((const float*)&c2a)[i] + w4.w * ((const float*)&c3a)[i]; \
                s[4 + i] = w4.x * ((const float*)&c0b)[i] + w4.y * ((const float*)&c1b)[i] \
                         + w4.z * ((const float*)&c2b)[i] + w4.w * ((const float*)&c3b)[i]; \
            }                                                                  \
        }                                                                      \
        uint4 aq;                                                              \
        aq.x = pkcvt(s[0], s[1]);                                              \
        aq.y = pkcvt(s[2], s[3]);                                              \
        aq.z = pkcvt(s[4], s[5]);                                              \
        aq.w = pkcvt(s[6], s[7]);                                              \
        const bf16x8 a = *(const bf16x8*)&aq;                                  \
        acc[0] = __builtin_amdgcn_mfma_f32_16x16x32_bf16(a, *(const bf16x8*)&b0##S, acc[0], 0, 0, 0); \
        acc[1] = __builtin_amdgcn_mfma_f32_16x16x32_bf16(a, *(const bf16x8*)&b1##S, acc[1], 0, 0, 0); \
        acc[2] = __builtin_amdgcn_mfma_f32_16x16x32_bf16(a, *(const bf16x8*)&b2##S, acc[2], 0, 0, 0); \
        acc[3] = __builtin_amdgcn_mfma_f32_16x16x32_bf16(a, *(const bf16x8*)&b3##S, acc[3], 0, 0, 0); \
    }

    float4 w4A; int4 o4A; int flA; uint4 q0A, q1A, q2A, q3A, b0A, b1A, b2A, b3A;
    float4 w4B; int4 o4B; int flB; uint4 q0B, q1B, q2B, q3B, b0B, b1B, b2B, b3B;

    TLOAD(A, 0)
    TLOAD(B, 1) TCONS(A)
    TLOAD(A, 2) TCONS(B)
    TLOAD(B, 3) TCONS(A)
    TLOAD(A, 4) TCONS(B)
    TLOAD(B, 5) TCONS(A)
    TLOAD(A, 6) TCONS(B)
    TLOAD(B, 7) TCONS(A)
    TLOAD(A, 8) TCONS(B)
                TCONS(A)

#undef TLOAD
#undef TCONS

    // ---- phase 4: pair reduction (red overlays dead xs5) ----
    __syncthreads();
    if (kw == 1) {
        #pragma unroll
        for (int nf = 0; nf < 4; ++nf) red[(pair * 4 + nf) * 64 + lane] = acc[nf];
    }
    __syncthreads();
    if (kw == 0) {
        #pragma unroll
        for (int nf = 0; nf < 4; ++nf) {
            const f32x4 o = red[(pair * 4 + nf) * 64 + lane];
            const int n  = nf * 16 + (lane & 15);
            const float bs = bias[n];
            const int m0 = pair * 16 + ((lane >> 4) * 4);
            #pragma unroll
            for (int r = 0; r < 4; ++r) {
                out[(size_t)(pix0 + m0 + r) * COUT + n] = acc[nf][r] + o[r] + bs;
            }
        }
    }
}

extern "C" void kernel_launch(void* const* d_in, const int* in_sizes, int n_in,
                              void* d_out, int out_size, void* d_ws, size_t ws_size,
                              hipStream_t stream)
{
    const float* x     = (const float*)d_in[0];
    const float* wmain = (const float*)d_in[1];
    const float* bias  = (const float*)d_in[2];
    const float* wofs  = (const float*)d_in[3];
    const float* bofs  = (const float*)d_in[4];
    float* out = (float*)d_out;
    uint4* wb  = (uint4*)d_ws;                          // 73728 B
    uint4* wf  = (uint4*)((char*)d_ws + 73728);         // 36864 B

    weight_transform<<<108, 64, 0, stream>>>(wmain, wofs, wb, wf);
    dcn_fused<<<NPIX / TMB, 256, 0, stream>>>(x, wb, wf, bias, bofs, out);
}